// Round 10
// baseline (515.810 us; speedup 1.0000x reference)
//
#include <hip/hip_runtime.h>
#include <math.h>

#define DEV __device__ __forceinline__

typedef __attribute__((ext_vector_type(8))) short bf16x8;
typedef __attribute__((ext_vector_type(4))) float f32x4;

DEV short f2bf(float v) {
    union { float f; unsigned u; } c; c.f = v;
    unsigned r = c.u + 0x7fffu + ((c.u >> 16) & 1u);   // RNE
    return (short)(r >> 16);
}
DEV float bf2f(short s) {
    return __uint_as_float(((unsigned)(unsigned short)s) << 16);
}
// 2x f32 -> packed bf16 in one VALU op
DEV unsigned cvt_pk(float lo, float hi) {
    unsigned r;
    asm("v_cvt_pk_bf16_f32 %0, %1, %2" : "=v"(r) : "v"(lo), "v"(hi));
    return r;
}
DEV uint2 pk4(const float4 v) {
    uint2 r; r.x = cvt_pk(v.x, v.y); r.y = cvt_pk(v.z, v.w); return r;
}

// ===========================================================================
// Weight packing
// ===========================================================================
#define NPACK 20
struct PackJobs {
    const float* W[NPACK];
    const float* Wsub[NPACK];
    int KIN[NPACK];
    int NOUT[NPACK];
    int end[NPACK];
};

__global__ __launch_bounds__(256)
void pack_all(PackJobs j, short* __restrict__ out, int total)
{
    const int idx = blockIdx.x * 256 + threadIdx.x;
    if (idx >= total) return;
    int job = 0;
    while (idx >= j.end[job]) ++job;
    const int base = job ? j.end[job - 1] : 0;
    const int w = idx - base;
    const int nout = j.NOUT[job];
    const int per_ks = nout * 32;
    const int ks = w / per_ks;
    const int r  = w - ks * per_ks;
    const int n  = r >> 5;
    const int kg = (r >> 3) & 3;
    const int i  = r & 7;
    const int k  = ks * 32 + kg * 8 + i;
    float val = 0.0f;
    if (k < j.KIN[job]) {
        val = j.W[job][(size_t)k * nout + n];
        if (j.Wsub[job]) val -= j.Wsub[job][(size_t)k * nout + n];
    }
    out[idx] = f2bf(val);
}

// ===========================================================================
// Sorting by dst
// ===========================================================================
__global__ __launch_bounds__(256)
void hist_kernel(const int* __restrict__ dst, int* __restrict__ cnt, int E)
{
    const int e = blockIdx.x * 256 + threadIdx.x;
    if (e < E) atomicAdd(&cnt[dst[e]], 1);
}

__global__ __launch_bounds__(1024)
void scan_kernel(int* __restrict__ cnt, int NB)
{
    __shared__ int part[1024];
    const int t = threadIdx.x;
    const int CH = (NB + 1023) >> 10;
    const int base = t * CH;
    int s = 0;
    for (int k = 0; k < CH; ++k) { const int i = base + k; if (i < NB) s += cnt[i]; }
    part[t] = s;
    __syncthreads();
    for (int off = 1; off < 1024; off <<= 1) {
        const int add = (t >= off) ? part[t - off] : 0;
        __syncthreads();
        part[t] += add;
        __syncthreads();
    }
    int run = part[t] - s;
    for (int k = 0; k < CH; ++k) {
        const int i = base + k;
        if (i < NB) { const int c = cnt[i]; cnt[i] = run; run += c; }
    }
}

__global__ __launch_bounds__(256)
void scatter_kernel(const int* __restrict__ src, const int* __restrict__ dst,
                    const float* __restrict__ ea, int* __restrict__ cursor,
                    int* __restrict__ sSrc, int* __restrict__ sDst,
                    short* __restrict__ eaB, int E)
{
    const int e = blockIdx.x * 256 + threadIdx.x;
    if (e >= E) return;
    const int d = dst[e];
    const int p = atomicAdd(&cursor[d], 1);
    sSrc[p] = src[e];
    sDst[p] = d;
    const float4 a = ((const float4*)ea)[e];
    *(uint2*)(eaB + (size_t)p * 4) = pk4(a);
}

// ===========================================================================
// MFMA GEMM over an LDS row-tile: wave = 16 rows x 128 cols
// ===========================================================================
template<int KP, int FSTR, int NOUT, bool BIAS>
DEV void mfma_gemm(const short* aLds, const short* __restrict__ Wpk,
                   const float* __restrict__ b, int row0, int c0, int lane,
                   f32x4 (&acc)[8])
{
    const int l15 = lane & 15;
    const int lg  = lane >> 4;
#pragma unroll
    for (int f = 0; f < 8; ++f) {
        if (BIAS) {
            const float bv = b[c0 + f * 16 + l15];
            acc[f] = (f32x4){bv, bv, bv, bv};
        } else {
            acc[f] = (f32x4){0.f, 0.f, 0.f, 0.f};
        }
    }
    const short* arow  = aLds + (row0 + l15) * FSTR + lg * 8;
    const short* wbase = Wpk + (size_t)(c0 + l15) * 32 + lg * 8;
#pragma unroll
    for (int ks = 0; ks < KP / 32; ++ks) {
        const bf16x8 av = *(const bf16x8*)(arow + ks * 32);
        const short* wp = wbase + (size_t)ks * NOUT * 32;
#pragma unroll
        for (int f = 0; f < 8; ++f) {
            const bf16x8 bv = *(const bf16x8*)(wp + f * 512);
            acc[f] = __builtin_amdgcn_mfma_f32_16x16x32_bf16(av, bv, acc[f], 0, 0, 0);
        }
    }
}

// relu(acc) -> packed bf16 rows in LDS
template<int OSTR>
DEV void pack_relu(const f32x4 (&acc)[8], short* out, int row0, int c0, int lane)
{
    const int l15 = lane & 15;
    const int lg  = lane >> 4;
#pragma unroll
    for (int f = 0; f < 8; ++f)
#pragma unroll
        for (int i = 0; i < 4; ++i) {
            const int row = row0 + lg * 4 + i;
            const int col = c0 + f * 16 + l15;
            const float vv = fmaxf(acc[f][i], 0.0f);
            const float o = __shfl_xor(vv, 1);
            if (!(lane & 1))
                *(unsigned*)&out[row * OSTR + col] = cvt_pk(vv, o);
        }
}

// acc -> bf16 global rows (paired 4-byte stores)
DEV void store_bf16(const f32x4 (&acc)[8], short* __restrict__ out,
                    int n0, int wave, int lane, int N)
{
    const int l15 = lane & 15;
    const int lg  = lane >> 4;
#pragma unroll
    for (int f = 0; f < 8; ++f)
#pragma unroll
        for (int i = 0; i < 4; ++i) {
            const float vv = acc[f][i];
            const float o = __shfl_xor(vv, 1);
            if (!(lane & 1)) {
                const int n = n0 + wave * 16 + lg * 4 + i;
                if (n < N)
                    *(unsigned*)&out[(size_t)n * 128 + f * 16 + l15] = cvt_pk(vv, o);
            }
        }
}

// ===========================================================================
// Layer-1 per-node precompute: u = x@(W1a-W1b)+b1, v = x@W1b (bf16),
// sq = ||x||^2, xB = bf16 x.
// ===========================================================================
template<int FIN, int FSTR>
__global__ __launch_bounds__(256)
void uv_pre(const float* __restrict__ xin,
            const short* __restrict__ Wd, const float* __restrict__ b1,
            const short* __restrict__ Wb,
            short* __restrict__ uB, short* __restrict__ vB,
            float* __restrict__ sq, short* __restrict__ xB, int N)
{
    __shared__ __align__(16) short feat[64 * FSTR];
    const int tid = threadIdx.x, lane = tid & 63, wave = tid >> 6;
    const int n0 = blockIdx.x * 64;
    {
        const int r = tid >> 2, s = tid & 3, n = n0 + r;
        short* frow = feat + r * FSTR;
        if (n < N) {
            const float4* xr = (const float4*)(xin + (size_t)n * FIN);
            float ss = 0.f;
#pragma unroll
            for (int d4 = s; d4 < FIN / 4; d4 += 4) {
                const float4 a = xr[d4];
                ss += a.x * a.x + a.y * a.y + a.z * a.z + a.w * a.w;
                const uint2 sv = pk4(a);
                *(uint2*)(frow + d4 * 4) = sv;
                *(uint2*)(xB + (size_t)n * FIN + d4 * 4) = sv;
            }
            ss += __shfl_xor(ss, 1); ss += __shfl_xor(ss, 2);
            if (s == 0) sq[n] = ss;
        } else {
            for (int d = s * 4; d < FIN; d += 16) *(short4*)(frow + d) = make_short4(0, 0, 0, 0);
        }
    }
    asm volatile("s_waitcnt lgkmcnt(0)" ::: "memory");
    f32x4 acc[8];
    mfma_gemm<FIN, FSTR, 128, true>(feat, Wd, b1, wave * 16, 0, lane, acc);
    store_bf16(acc, uB, n0, wave, lane, N);
    mfma_gemm<FIN, FSTR, 128, false>(feat, Wb, nullptr, wave * 16, 0, lane, acc);
    store_bf16(acc, vB, n0, wave, lane, N);
}

// ===========================================================================
// Edge conv v8: 64 edges/block, 512 threads, 8 waves col-split (16 cols/wave)
// feat=[p, e1, e2, ea4, pad]; uv=u[dst]+v[src] in h1s; h1=relu(feat@Wp+uv);
// m=relu(h1@W2+b2) -> mbuf (feat region when FIN=128); run-max -> atomicMax.
// ===========================================================================
template<int FIN>
__global__ __launch_bounds__(512, 8)
void edge_conv8(const short* __restrict__ xB,
                const int* __restrict__ sSrc, const int* __restrict__ sDst,
                const short* __restrict__ eaB, const float* __restrict__ sq,
                const short* __restrict__ uB, const short* __restrict__ vB,
                const short* __restrict__ W1pk, const short* __restrict__ W2pk,
                const float* __restrict__ b2,
                float* __restrict__ agg, int E, int swzQ, int swzR)
{
    constexpr int KPP  = FIN + 32;
    constexpr int FSTR = KPP + 8;        // 72 / 168
    constexpr int H1STR = 136;
    constexpr bool MBF = (FSTR >= 132);  // m fits in feat region?
    constexpr int MS = MBF ? FSTR : H1STR;
    __shared__ __align__(16) short feat[64 * FSTR];
    __shared__ __align__(16) short h1s[64 * H1STR];
    __shared__ int dstv[64];
    const int tid = threadIdx.x, lane = tid & 63, wave = tid >> 6;
    const int l15 = lane & 15, lg = lane >> 4;
    int bid = blockIdx.x;
    {   // bijective XCD-chunk swizzle
        const int xcd = bid & 7, idx = bid >> 3;
        bid = (xcd < swzR ? xcd * (swzQ + 1)
                          : swzR * (swzQ + 1) + (xcd - swzR) * swzQ) + idx;
    }
    const int e0 = bid * 64;
    const int c0 = wave * 16;

    // ---- stage 1: p features + tail; uv = u[dst]+v[src] (8 thr/edge) ----
    {
        const int r = tid >> 3, s = tid & 7, e = e0 + r;
        short* frow = feat + r * FSTR;
        short* urow = h1s + r * H1STR;
        if (e < E) {
            const int si = sSrc[e], di = sDst[e];
            if (s == 0) dstv[r] = di;
            float sp = 0.f;
#pragma unroll
            for (int c = s; c < FIN / 8; c += 8) {
                const bf16x8 a = *(const bf16x8*)(xB + (size_t)si * FIN + c * 8);
                const bf16x8 b = *(const bf16x8*)(xB + (size_t)di * FIN + c * 8);
                float p[8];
#pragma unroll
                for (int jj = 0; jj < 8; ++jj) {
                    p[jj] = bf2f(a[jj]) * bf2f(b[jj]);
                    sp += p[jj];
                }
                uint4 w;
                w.x = cvt_pk(p[0], p[1]); w.y = cvt_pk(p[2], p[3]);
                w.z = cvt_pk(p[4], p[5]); w.w = cvt_pk(p[6], p[7]);
                *(uint4*)(frow + c * 8) = w;
            }
            sp += __shfl_xor(sp, 1); sp += __shfl_xor(sp, 2); sp += __shfl_xor(sp, 4);
            if (s == 0) {
                const float e1v = sqrtf(fmaxf(sq[si] + sq[di] - 2.f * sp, 0.f));
                *(unsigned*)(frow + FIN) = cvt_pk(e1v, sp);
            }
            if (s == 1) {
                const short4 ea = *(const short4*)(eaB + (size_t)e * 4);
                *(short2*)(frow + FIN + 2) = make_short2(ea.x, ea.y);
                *(short2*)(frow + FIN + 4) = make_short2(ea.z, ea.w);
            }
            for (int d = FIN + 6 + s; d < KPP; d += 8) frow[d] = 0;
#pragma unroll
            for (int c = s; c < 16; c += 8) {
                const bf16x8 uu = *(const bf16x8*)(uB + (size_t)di * 128 + c * 8);
                const bf16x8 vv = *(const bf16x8*)(vB + (size_t)si * 128 + c * 8);
                float o[8];
#pragma unroll
                for (int jj = 0; jj < 8; ++jj)
                    o[jj] = bf2f(uu[jj]) + bf2f(vv[jj]);
                uint4 w;
                w.x = cvt_pk(o[0], o[1]); w.y = cvt_pk(o[2], o[3]);
                w.z = cvt_pk(o[4], o[5]); w.w = cvt_pk(o[6], o[7]);
                *(uint4*)(urow + c * 8) = w;
            }
        } else {
            if (s == 0) dstv[r] = -1;
            for (int d = s * 4; d < KPP; d += 32) *(short4*)(frow + d) = make_short4(0, 0, 0, 0);
            for (int d = s * 4; d < 128; d += 32) *(short4*)(urow + d) = make_short4(0, 0, 0, 0);
        }
    }
    __syncthreads();

    // ---- GEMM1 (col-split) ----
    f32x4 acc[4];
#pragma unroll
    for (int sb = 0; sb < 4; ++sb) acc[sb] = (f32x4){0.f, 0.f, 0.f, 0.f};
    {
        const short* wb = W1pk + (size_t)(c0 + l15) * 32 + lg * 8;
#pragma unroll
        for (int ks = 0; ks < KPP / 32; ++ks) {
            const bf16x8 bv = *(const bf16x8*)(wb + (size_t)ks * 4096);
#pragma unroll
            for (int sb = 0; sb < 4; ++sb) {
                const bf16x8 av =
                    *(const bf16x8*)(feat + (sb * 16 + l15) * FSTR + ks * 32 + lg * 8);
                acc[sb] = __builtin_amdgcn_mfma_f32_16x16x32_bf16(av, bv, acc[sb], 0, 0, 0);
            }
        }
    }
    // h1 = relu(acc + uv)
#pragma unroll
    for (int sb = 0; sb < 4; ++sb)
#pragma unroll
        for (int i = 0; i < 4; ++i) {
            const int row = sb * 16 + lg * 4 + i;
            const int col = c0 + l15;
            float vv = acc[sb][i] + bf2f(h1s[row * H1STR + col]);
            vv = fmaxf(vv, 0.0f);
            const float o = __shfl_xor(vv, 1);
            if (!(lane & 1))
                *(unsigned*)&h1s[row * H1STR + col] = cvt_pk(vv, o);
        }
    __syncthreads();

    // ---- GEMM2 (col-split) ----
    {
        const float bv0 = b2[c0 + l15];
#pragma unroll
        for (int sb = 0; sb < 4; ++sb) acc[sb] = (f32x4){bv0, bv0, bv0, bv0};
    }
    {
        const short* wb = W2pk + (size_t)(c0 + l15) * 32 + lg * 8;
#pragma unroll
        for (int ks = 0; ks < 4; ++ks) {
            const bf16x8 bv = *(const bf16x8*)(wb + (size_t)ks * 4096);
#pragma unroll
            for (int sb = 0; sb < 4; ++sb) {
                const bf16x8 av =
                    *(const bf16x8*)(h1s + (sb * 16 + l15) * H1STR + ks * 32 + lg * 8);
                acc[sb] = __builtin_amdgcn_mfma_f32_16x16x32_bf16(av, bv, acc[sb], 0, 0, 0);
            }
        }
    }
    short* mb = MBF ? feat : h1s;        // FIN=128: feat region free during GEMM2
    if (!MBF) __syncthreads();           // FIN=32: must wait for all h1 reads
    // ---- m -> bf16 mbuf ----
#pragma unroll
    for (int sb = 0; sb < 4; ++sb)
#pragma unroll
        for (int i = 0; i < 4; ++i) {
            const int row = sb * 16 + lg * 4 + i;
            const int col = c0 + l15;
            const float vv = fmaxf(acc[sb][i], 0.0f);
            const float o = __shfl_xor(vv, 1);
            if (!(lane & 1))
                *(unsigned*)&mb[row * MS + col] = cvt_pk(vv, o);
        }
    __syncthreads();

    // ---- run-max over sorted dst (4 strips of 16 rows), zero-skip ----
    {
        const int c  = tid & 127;
        const int rh = tid >> 7;
        int cur = -1;
        float mx = 0.0f;
#pragma unroll 4
        for (int i2 = 0; i2 < 16; ++i2) {
            const int row = rh * 16 + i2;
            const int d = dstv[row];
            const float val = bf2f(mb[row * MS + c]);
            if (d != cur) {
                if (cur >= 0 && mx > 0.f)
                    atomicMax((int*)agg + (size_t)cur * 128 + c, __float_as_int(mx));
                cur = d;
                mx = val;
            } else {
                mx = fmaxf(mx, val);
            }
        }
        if (cur >= 0 && mx > 0.f)
            atomicMax((int*)agg + (size_t)cur * 128 + c, __float_as_int(mx));
    }
}

// ===========================================================================
// Fused node MLP + next-layer uv precompute (barrier-free, wave-local).
// y = relu(relu([x,agg]@W1+b1)@W2+b2) (+x); out=y; xB=bf16(y); sq=||y||^2;
// u = y@WdN+b1N; v = y@WbN.
// ===========================================================================
template<int FIN, int KP, int FSTR, bool RES>
__global__ __launch_bounds__(256)
void node_uv(const float* __restrict__ xin, const float* __restrict__ agg,
             const short* __restrict__ W1pk, const float* __restrict__ b1,
             const short* __restrict__ W2pk, const float* __restrict__ b2,
             float* __restrict__ out,
             const short* __restrict__ WdN, const float* __restrict__ b1N,
             const short* __restrict__ WbN,
             short* __restrict__ uB, short* __restrict__ vB,
             float* __restrict__ sq, short* __restrict__ xB, int N)
{
    constexpr int H1STR = 136;
    __shared__ __align__(16) short sh[64 * FSTR + 64 * H1STR];
    short* feat = sh;
    short* h1s  = sh + 64 * FSTR;
    const int tid = threadIdx.x, lane = tid & 63, wave = tid >> 6;
    const int l15 = lane & 15, lg = lane >> 4;
    const int n0 = blockIdx.x * 64;

    {
        const int r = tid >> 2, s = tid & 3, n = n0 + r;
        short* frow = feat + r * FSTR;
        if (n < N) {
            const float4* xr = (const float4*)(xin + (size_t)n * FIN);
            const float4* ar = (const float4*)(agg + (size_t)n * 128);
#pragma unroll
            for (int d4 = s; d4 < FIN / 4; d4 += 4)
                *(uint2*)(frow + d4 * 4) = pk4(xr[d4]);
#pragma unroll
            for (int d4 = s; d4 < 32; d4 += 4)
                *(uint2*)(frow + FIN + d4 * 4) = pk4(ar[d4]);
        } else {
            for (int d = s * 4; d < KP; d += 16) *(short4*)(frow + d) = make_short4(0, 0, 0, 0);
        }
    }
    asm volatile("s_waitcnt lgkmcnt(0)" ::: "memory");

    f32x4 acc[8];
    mfma_gemm<KP, FSTR, 128, true>(feat, W1pk, b1, wave * 16, 0, lane, acc);
    pack_relu<H1STR>(acc, h1s, wave * 16, 0, lane);
    asm volatile("s_waitcnt lgkmcnt(0)" ::: "memory");
    mfma_gemm<128, H1STR, 128, true>(h1s, W2pk, b2, wave * 16, 0, lane, acc);

    // ---- epilogue: y -> out (f32), xB+h1s (bf16), sq ----
    {
        float ss[4] = {0.f, 0.f, 0.f, 0.f};
#pragma unroll
        for (int f = 0; f < 8; ++f)
#pragma unroll
            for (int i = 0; i < 4; ++i) {
                const int n = n0 + wave * 16 + lg * 4 + i;
                const int c = f * 16 + l15;
                float v = fmaxf(acc[f][i], 0.0f);
                if (RES && n < N) v += xin[(size_t)n * 128 + c];
                if (n < N) out[(size_t)n * 128 + c] = v;
                ss[i] += v * v;
                const float o = __shfl_xor(v, 1);
                if (!(lane & 1)) {
                    const unsigned pk = cvt_pk(v, o);
                    const int row = wave * 16 + lg * 4 + i;
                    *(unsigned*)&h1s[row * H1STR + c] = pk;
                    if (n < N) *(unsigned*)&xB[(size_t)n * 128 + c] = pk;
                }
            }
#pragma unroll
        for (int i = 0; i < 4; ++i) {
            ss[i] += __shfl_xor(ss[i], 1);
            ss[i] += __shfl_xor(ss[i], 2);
            ss[i] += __shfl_xor(ss[i], 4);
            ss[i] += __shfl_xor(ss[i], 8);
            const int n = n0 + wave * 16 + lg * 4 + i;
            if (l15 == 0 && n < N) sq[n] = ss[i];
        }
    }
    asm volatile("s_waitcnt lgkmcnt(0)" ::: "memory");

    // ---- u/v GEMMs from bf16 y in h1s ----
    mfma_gemm<128, H1STR, 128, true>(h1s, WdN, b1N, wave * 16, 0, lane, acc);
    store_bf16(acc, uB, n0, wave, lane, N);
    mfma_gemm<128, H1STR, 128, false>(h1s, WbN, nullptr, wave * 16, 0, lane, acc);
    store_bf16(acc, vB, n0, wave, lane, N);
}

// ===========================================================================
// Fused layer-3 node MLP + fusion MLP: 32 rows/block, 128 threads, 2 waves.
// x3 = relu(relu([x2,agg]@W1+b1)@W2+b2)+x2 (registers only);
// out = relu(relu([x1,x2,x3]@fW1+fb1)@fW2+fb2).
// ===========================================================================
__global__ __launch_bounds__(128)
void node_fusion(const float* __restrict__ x1, const float* __restrict__ x2,
                 const float* __restrict__ agg,
                 const short* __restrict__ W1pk, const float* __restrict__ b1,
                 const short* __restrict__ W2pk, const float* __restrict__ b2,
                 const short* __restrict__ fW1, const float* __restrict__ fb1,
                 const short* __restrict__ fW2, const float* __restrict__ fb2,
                 float* __restrict__ out, int N)
{
    constexpr int NSTR = 264;     // node feat stride (K=256)
    constexpr int H1N  = 136;     // node h1 stride
    constexpr int FSF  = 392;     // fusion feat stride (K=384)
    constexpr int H1F  = 264;     // fusion h1 stride (256 cols)
    __shared__ __align__(16) short sh[32 * FSF + 32 * H1F];   // 20992 shorts
    short* featN = sh;                 // [32][264]
    short* h1N   = sh + 32 * FSF;      // [32][136] (inside future h1F region)
    short* featF = sh;                 // [32][392]
    short* h1F   = sh + 32 * FSF;      // [32][264]
    const int tid = threadIdx.x, lane = tid & 63, wave = tid >> 6;
    const int l15 = lane & 15, lg = lane >> 4;
    const int n0 = blockIdx.x * 32;

    // ---- node stage 1: featN = [bf16(x2), bf16(agg)] ----
    {
        const int r = tid >> 2, s = tid & 3, n = n0 + r;
        short* frow = featN + r * NSTR;
        if (n < N) {
            const float4* xr = (const float4*)(x2 + (size_t)n * 128);
            const float4* ar = (const float4*)(agg + (size_t)n * 128);
#pragma unroll
            for (int d4 = s; d4 < 32; d4 += 4) {
                *(uint2*)(frow + d4 * 4)       = pk4(xr[d4]);
                *(uint2*)(frow + 128 + d4 * 4) = pk4(ar[d4]);
            }
        } else {
            for (int d = s * 4; d < 256; d += 16) *(short4*)(frow + d) = make_short4(0, 0, 0, 0);
        }
    }
    asm volatile("s_waitcnt lgkmcnt(0)" ::: "memory");

    f32x4 acc[8];
    mfma_gemm<256, NSTR, 128, true>(featN, W1pk, b1, wave * 16, 0, lane, acc);
    pack_relu<H1N>(acc, h1N, wave * 16, 0, lane);
    asm volatile("s_waitcnt lgkmcnt(0)" ::: "memory");
    mfma_gemm<128, H1N, 128, true>(h1N, W2pk, b2, wave * 16, 0, lane, acc);
    // y = x3 = relu(acc) + x2  (held in acc across the barrier)
#pragma unroll
    for (int f = 0; f < 8; ++f)
#pragma unroll
        for (int i = 0; i < 4; ++i) {
            const int n = n0 + wave * 16 + lg * 4 + i;
            float v = fmaxf(acc[f][i], 0.0f);
            if (n < N) v += x2[(size_t)n * 128 + f * 16 + l15];
            acc[f][i] = v;
        }
    __syncthreads();   // all waves done with featN/h1N -> safe to build featF

    // ---- fusion feat: [bf16(x1), bf16(x2), bf16(x3)] ----
    {
        const int r = tid >> 2, s = tid & 3, n = n0 + r;
        short* frow = featF + r * FSF;
        if (n < N) {
            const float4* a1 = (const float4*)(x1 + (size_t)n * 128);
            const float4* a2 = (const float4*)(x2 + (size_t)n * 128);
#pragma unroll
            for (int d4 = s; d4 < 32; d4 += 4) {
                *(uint2*)(frow + d4 * 4)       = pk4(a1[d4]);
                *(uint2*)(frow + 128 + d4 * 4) = pk4(a2[d4]);
            }
        } else {
            for (int d = s * 4; d < 256; d += 16) *(short4*)(frow + d) = make_short4(0, 0, 0, 0);
            for (int d = 256 + s * 4; d < 384; d += 16) *(short4*)(frow + d) = make_short4(0, 0, 0, 0);
        }
    }
    // x3 part from registers (C-layout, wave-local rows)
#pragma unroll
    for (int f = 0; f < 8; ++f)
#pragma unroll
        for (int i = 0; i < 4; ++i) {
            const int row = wave * 16 + lg * 4 + i;
            const float v = acc[f][i];
            const float o = __shfl_xor(v, 1);
            if (!(lane & 1))
                *(unsigned*)&featF[row * FSF + 256 + f * 16 + l15] = cvt_pk(v, o);
        }
    asm volatile("s_waitcnt lgkmcnt(0)" ::: "memory");

    // ---- fusion GEMMs ----
#pragma unroll
    for (int c0 = 0; c0 < 256; c0 += 128) {
        mfma_gemm<384, FSF, 256, true>(featF, fW1, fb1, wave * 16, c0, lane, acc);
        pack_relu<H1F>(acc, h1F, wave * 16, c0, lane);
    }
    asm volatile("s_waitcnt lgkmcnt(0)" ::: "memory");
    mfma_gemm<256, H1F, 128, true>(h1F, fW2, fb2, wave * 16, 0, lane, acc);
#pragma unroll
    for (int f = 0; f < 8; ++f)
#pragma unroll
        for (int i = 0; i < 4; ++i) {
            const int n = n0 + wave * 16 + lg * 4 + i;
            if (n < N)
                out[(size_t)n * 128 + f * 16 + l15] = fmaxf(acc[f][i], 0.0f);
        }
}

// ===========================================================================
extern "C" void kernel_launch(void* const* d_in, const int* in_sizes, int n_in,
                              void* d_out, int out_size, void* d_ws, size_t ws_size,
                              hipStream_t stream)
{
    const float* x    = (const float*)d_in[0];
    const int*   eidx = (const int*)d_in[1];
    const float* ea   = (const float*)d_in[2];

    const float* c1_eW1 = (const float*)d_in[3];
    const float* c1_eb1 = (const float*)d_in[4];
    const float* c1_eW2 = (const float*)d_in[5];
    const float* c1_eb2 = (const float*)d_in[6];
    const float* c1_lW1 = (const float*)d_in[7];
    const float* c1_lb1 = (const float*)d_in[8];
    const float* c1_lW2 = (const float*)d_in[9];
    const float* c1_lb2 = (const float*)d_in[10];

    const float* c2_eW1 = (const float*)d_in[11];
    const float* c2_eb1 = (const float*)d_in[12];
    const float* c2_eW2 = (const float*)d_in[13];
    const float* c2_eb2 = (const float*)d_in[14];
    const float* c2_lW1 = (const float*)d_in[15];
    const float* c2_lb1 = (const float*)d_in[16];
    const float* c2_lW2 = (const float*)d_in[17];
    const float* c2_lb2 = (const float*)d_in[18];

    const float* c3_eW1 = (const float*)d_in[19];
    const float* c3_eb1 = (const float*)d_in[20];
    const float* c3_eW2 = (const float*)d_in[21];
    const float* c3_eb2 = (const float*)d_in[22];
    const float* c3_lW1 = (const float*)d_in[23];
    const float* c3_lb1 = (const float*)d_in[24];
    const float* c3_lW2 = (const float*)d_in[25];
    const float* c3_lb2 = (const float*)d_in[26];

    const float* fus_W1 = (const float*)d_in[27];
    const float* fus_b1 = (const float*)d_in[28];
    const float* fus_W2 = (const float*)d_in[29];
    const float* fus_b2 = (const float*)d_in[30];

    const int N = in_sizes[0] / 32;   // 25000
    const int E = in_sizes[1] / 2;    // 400000
    const int* srcI = eidx;
    const int* dstI = eidx + E;

    const size_t NP = (size_t)N * 128;
    float* ws  = (float*)d_ws;
    float* x1  = ws;
    float* x2  = x1 + NP;
    float* agg = x2 + NP;
    float* sq  = agg + NP;
    int* cursor = (int*)(sq + N);
    int* sSrc   = cursor + 25024;
    int* sDst   = sSrc + E;
    short* eaB  = (short*)(sDst + E);
    short* uB   = eaB + (size_t)E * 4;
    short* vB   = uB + NP;
    short* xB   = vB + NP;
    short* wpk  = xB + NP;

    // packed-weight offsets (shorts)
    short* e1Wd = wpk + 0;        // KIN 32  KP 32   (W1a-W1b)
    short* e1Wb = wpk + 4096;     // KIN 32  KP 32   (W1b)
    short* e1Wp = wpk + 8192;     // KIN 38  KP 64   (p rows + e1,e2,ea)
    short* e1W2 = wpk + 16384;    // KIN 128 KP 128
    short* e2Wd = wpk + 32768;    // KIN 128 KP 128
    short* e2Wb = wpk + 49152;
    short* e2Wp = wpk + 65536;    // KIN 134 KP 160
    short* e2W2 = wpk + 86016;
    short* e3Wd = wpk + 102400;
    short* e3Wb = wpk + 118784;
    short* e3Wp = wpk + 135168;
    short* e3W2 = wpk + 155648;
    short* n1W1 = wpk + 172032;   // KIN 160 KP 160
    short* n1W2 = wpk + 192512;
    short* n2W1 = wpk + 208896;   // KIN 256 KP 256
    short* n2W2 = wpk + 241664;
    short* n3W1 = wpk + 258048;
    short* n3W2 = wpk + 290816;
    short* fW1  = wpk + 307200;   // KIN 384 NOUT 256
    short* fW2  = wpk + 405504;   // KIN 256
    const int packTotal = 438272;

    PackJobs pj;
    const float* pw[NPACK] = {
        c1_eW1, c1_eW1 + 32 * 128, c1_eW1 + 64 * 128, c1_eW2,
        c2_eW1, c2_eW1 + 128 * 128, c2_eW1 + 256 * 128, c2_eW2,
        c3_eW1, c3_eW1 + 128 * 128, c3_eW1 + 256 * 128, c3_eW2,
        c1_lW1, c1_lW2, c2_lW1, c2_lW2, c3_lW1, c3_lW2,
        fus_W1, fus_W2};
    const float* ps[NPACK] = {
        c1_eW1 + 32 * 128, nullptr, nullptr, nullptr,
        c2_eW1 + 128 * 128, nullptr, nullptr, nullptr,
        c3_eW1 + 128 * 128, nullptr, nullptr, nullptr,
        nullptr, nullptr, nullptr, nullptr, nullptr, nullptr,
        nullptr, nullptr};
    const int pk_kin[NPACK]  = {32, 32, 38, 128, 128, 128, 134, 128,
                                128, 128, 134, 128, 160, 128, 256, 128, 256, 128,
                                384, 256};
    const int pk_nout[NPACK] = {128, 128, 128, 128, 128, 128, 128, 128,
                                128, 128, 128, 128, 128, 128, 128, 128, 128, 128,
                                256, 128};
    const int pk_end[NPACK]  = {4096, 8192, 16384, 32768, 49152, 65536, 86016, 102400,
                                118784, 135168, 155648, 172032, 192512, 208896, 241664,
                                258048, 290816, 307200, 405504, 438272};
    for (int i = 0; i < NPACK; ++i) {
        pj.W[i] = pw[i]; pj.Wsub[i] = ps[i];
        pj.KIN[i] = pk_kin[i]; pj.NOUT[i] = pk_nout[i]; pj.end[i] = pk_end[i];
    }
    pack_all<<<(packTotal + 255) / 256, 256, 0, stream>>>(pj, wpk, packTotal);

    // ---- sort edges by dst ----
    const int eblk = (E + 255) / 256;
    hipMemsetAsync(cursor, 0, 25024 * sizeof(int), stream);
    hist_kernel<<<eblk, 256, 0, stream>>>(dstI, cursor, E);
    scan_kernel<<<1, 1024, 0, stream>>>(cursor, N);
    scatter_kernel<<<eblk, 256, 0, stream>>>(srcI, dstI, ea, cursor, sSrc, sDst, eaB, E);

    const int eblocks = (E + 63) / 64;
    const int nblocks = (N + 63) / 64;
    const int fblocks = (N + 31) / 32;
    const int swzQ = eblocks / 8, swzR = eblocks % 8;
    const size_t aggBytes = NP * sizeof(float);

    // ---- layer 1 (FIN=32) ----
    uv_pre<32, 40><<<nblocks, 256, 0, stream>>>(x, e1Wd, c1_eb1, e1Wb, uB, vB, sq, xB, N);
    hipMemsetAsync(agg, 0, aggBytes, stream);
    edge_conv8<32><<<eblocks, 512, 0, stream>>>(
        xB, sSrc, sDst, eaB, sq, uB, vB, e1Wp, e1W2, c1_eb2, agg, E, swzQ, swzR);
    node_uv<32, 160, 168, false><<<nblocks, 256, 0, stream>>>(
        x, agg, n1W1, c1_lb1, n1W2, c1_lb2, x1,
        e2Wd, c2_eb1, e2Wb, uB, vB, sq, xB, N);

    // ---- layer 2 (FIN=128, residual) ----
    hipMemsetAsync(agg, 0, aggBytes, stream);
    edge_conv8<128><<<eblocks, 512, 0, stream>>>(
        xB, sSrc, sDst, eaB, sq, uB, vB, e2Wp, e2W2, c2_eb2, agg, E, swzQ, swzR);
    node_uv<128, 256, 264, true><<<nblocks, 256, 0, stream>>>(
        x1, agg, n2W1, c2_lb1, n2W2, c2_lb2, x2,
        e3Wd, c3_eb1, e3Wb, uB, vB, sq, xB, N);

    // ---- layer 3 (FIN=128, residual) + fusion ----
    hipMemsetAsync(agg, 0, aggBytes, stream);
    edge_conv8<128><<<eblocks, 512, 0, stream>>>(
        xB, sSrc, sDst, eaB, sq, uB, vB, e3Wp, e3W2, c3_eb2, agg, E, swzQ, swzR);
    node_fusion<<<fblocks, 128, 0, stream>>>(
        x1, x2, agg, n3W1, c3_lb1, n3W2, c3_lb2,
        fW1, fus_b1, fW2, fus_b2, (float*)d_out, N);
}

// Round 11
// 421.268 us; speedup vs baseline: 1.2244x; 1.2244x over previous
//
#include <hip/hip_runtime.h>
#include <math.h>

#define DEV __device__ __forceinline__

typedef __attribute__((ext_vector_type(8))) short bf16x8;
typedef __attribute__((ext_vector_type(4))) float f32x4;

DEV short f2bf(float v) {
    union { float f; unsigned u; } c; c.f = v;
    unsigned r = c.u + 0x7fffu + ((c.u >> 16) & 1u);   // RNE
    return (short)(r >> 16);
}
DEV float bf2f(short s) {
    return __uint_as_float(((unsigned)(unsigned short)s) << 16);
}
// 2x f32 -> packed bf16 in one VALU op
DEV unsigned cvt_pk(float lo, float hi) {
    unsigned r;
    asm("v_cvt_pk_bf16_f32 %0, %1, %2" : "=v"(r) : "v"(lo), "v"(hi));
    return r;
}
DEV uint2 pk4(const float4 v) {
    uint2 r; r.x = cvt_pk(v.x, v.y); r.y = cvt_pk(v.z, v.w); return r;
}

// ===========================================================================
// Weight packing (+ cursor zeroing for the sort)
// ===========================================================================
#define NPACK 20
struct PackJobs {
    const float* W[NPACK];
    const float* Wsub[NPACK];
    int KIN[NPACK];
    int NOUT[NPACK];
    int end[NPACK];
};

__global__ __launch_bounds__(256)
void pack_all(PackJobs j, short* __restrict__ out, int total,
              int* __restrict__ cursor)
{
    const int idx = blockIdx.x * 256 + threadIdx.x;
    if (idx < 25024) cursor[idx] = 0;
    if (idx >= total) return;
    int job = 0;
    while (idx >= j.end[job]) ++job;
    const int base = job ? j.end[job - 1] : 0;
    const int w = idx - base;
    const int nout = j.NOUT[job];
    const int per_ks = nout * 32;
    const int ks = w / per_ks;
    const int r  = w - ks * per_ks;
    const int n  = r >> 5;
    const int kg = (r >> 3) & 3;
    const int i  = r & 7;
    const int k  = ks * 32 + kg * 8 + i;
    float val = 0.0f;
    if (k < j.KIN[job]) {
        val = j.W[job][(size_t)k * nout + n];
        if (j.Wsub[job]) val -= j.Wsub[job][(size_t)k * nout + n];
    }
    out[idx] = f2bf(val);
}

// ===========================================================================
// Sorting by dst
// ===========================================================================
__global__ __launch_bounds__(256)
void hist_kernel(const int* __restrict__ dst, int* __restrict__ cnt, int E)
{
    const int e = blockIdx.x * 256 + threadIdx.x;
    if (e < E) atomicAdd(&cnt[dst[e]], 1);
}

__global__ __launch_bounds__(1024)
void scan_kernel(int* __restrict__ cnt, int NB)
{
    __shared__ int part[1024];
    const int t = threadIdx.x;
    const int CH = (NB + 1023) >> 10;
    const int base = t * CH;
    int s = 0;
    for (int k = 0; k < CH; ++k) { const int i = base + k; if (i < NB) s += cnt[i]; }
    part[t] = s;
    __syncthreads();
    for (int off = 1; off < 1024; off <<= 1) {
        const int add = (t >= off) ? part[t - off] : 0;
        __syncthreads();
        part[t] += add;
        __syncthreads();
    }
    int run = part[t] - s;
    for (int k = 0; k < CH; ++k) {
        const int i = base + k;
        if (i < NB) { const int c = cnt[i]; cnt[i] = run; run += c; }
    }
}

__global__ __launch_bounds__(256)
void scatter_kernel(const int* __restrict__ src, const int* __restrict__ dst,
                    const float* __restrict__ ea, int* __restrict__ cursor,
                    int* __restrict__ sSrc, int* __restrict__ sDst,
                    short* __restrict__ eaB, int E)
{
    const int e = blockIdx.x * 256 + threadIdx.x;
    if (e >= E) return;
    const int d = dst[e];
    const int p = atomicAdd(&cursor[d], 1);
    sSrc[p] = src[e];
    sDst[p] = d;
    const float4 a = ((const float4*)ea)[e];
    *(uint2*)(eaB + (size_t)p * 4) = pk4(a);
}

// ===========================================================================
// MFMA GEMM over an LDS row-tile (uv_pre only): wave = 16 rows x 128 cols
// ===========================================================================
template<int KP, int FSTR, int NOUT, bool BIAS>
DEV void mfma_gemm(const short* aLds, const short* __restrict__ Wpk,
                   const float* __restrict__ b, int row0, int c0, int lane,
                   f32x4 (&acc)[8])
{
    const int l15 = lane & 15;
    const int lg  = lane >> 4;
#pragma unroll
    for (int f = 0; f < 8; ++f) {
        if (BIAS) {
            const float bv = b[c0 + f * 16 + l15];
            acc[f] = (f32x4){bv, bv, bv, bv};
        } else {
            acc[f] = (f32x4){0.f, 0.f, 0.f, 0.f};
        }
    }
    const short* arow  = aLds + (row0 + l15) * FSTR + lg * 8;
    const short* wbase = Wpk + (size_t)(c0 + l15) * 32 + lg * 8;
#pragma unroll
    for (int ks = 0; ks < KP / 32; ++ks) {
        const bf16x8 av = *(const bf16x8*)(arow + ks * 32);
        const short* wp = wbase + (size_t)ks * NOUT * 32;
#pragma unroll
        for (int f = 0; f < 8; ++f) {
            const bf16x8 bv = *(const bf16x8*)(wp + f * 512);
            acc[f] = __builtin_amdgcn_mfma_f32_16x16x32_bf16(av, bv, acc[f], 0, 0, 0);
        }
    }
}

// acc -> bf16 global rows (paired 4-byte stores)
DEV void store_bf16(const f32x4 (&acc)[8], short* __restrict__ out,
                    int n0, int wave, int lane, int N)
{
    const int l15 = lane & 15;
    const int lg  = lane >> 4;
#pragma unroll
    for (int f = 0; f < 8; ++f)
#pragma unroll
        for (int i = 0; i < 4; ++i) {
            const float vv = acc[f][i];
            const float o = __shfl_xor(vv, 1);
            if (!(lane & 1)) {
                const int n = n0 + wave * 16 + lg * 4 + i;
                if (n < N)
                    *(unsigned*)&out[(size_t)n * 128 + f * 16 + l15] = cvt_pk(vv, o);
            }
        }
}

// ===========================================================================
// Layer-1 per-node precompute: u = x@(W1a-W1b)+b1, v = x@W1b (bf16),
// sq = ||x||^2, xB = bf16 x.  Also zeroes agg rows for layer-1 edge pass.
// ===========================================================================
template<int FIN, int FSTR>
__global__ __launch_bounds__(256)
void uv_pre(const float* __restrict__ xin,
            const short* __restrict__ Wd, const float* __restrict__ b1,
            const short* __restrict__ Wb,
            short* __restrict__ uB, short* __restrict__ vB,
            float* __restrict__ sq, short* __restrict__ xB,
            float* __restrict__ aggz, int N)
{
    __shared__ __align__(16) short feat[64 * FSTR];
    const int tid = threadIdx.x, lane = tid & 63, wave = tid >> 6;
    const int n0 = blockIdx.x * 64;
    {   // zero agg rows n0..n0+63 (deterministic: done before edge pass)
        float4 z = {0.f, 0.f, 0.f, 0.f};
        float4* ap = (float4*)(aggz + (size_t)n0 * 128);
#pragma unroll
        for (int i = 0; i < 8; ++i) ap[tid + i * 256] = z;
    }
    {
        const int r = tid >> 2, s = tid & 3, n = n0 + r;
        short* frow = feat + r * FSTR;
        if (n < N) {
            const float4* xr = (const float4*)(xin + (size_t)n * FIN);
            float ss = 0.f;
#pragma unroll
            for (int d4 = s; d4 < FIN / 4; d4 += 4) {
                const float4 a = xr[d4];
                ss += a.x * a.x + a.y * a.y + a.z * a.z + a.w * a.w;
                const uint2 sv = pk4(a);
                *(uint2*)(frow + d4 * 4) = sv;
                *(uint2*)(xB + (size_t)n * FIN + d4 * 4) = sv;
            }
            ss += __shfl_xor(ss, 1); ss += __shfl_xor(ss, 2);
            if (s == 0) sq[n] = ss;
        } else {
            for (int d = s * 4; d < FIN; d += 16) *(short4*)(frow + d) = make_short4(0, 0, 0, 0);
        }
    }
    asm volatile("s_waitcnt lgkmcnt(0)" ::: "memory");
    f32x4 acc[8];
    mfma_gemm<FIN, FSTR, 128, true>(feat, Wd, b1, wave * 16, 0, lane, acc);
    store_bf16(acc, uB, n0, wave, lane, N);
    mfma_gemm<FIN, FSTR, 128, false>(feat, Wb, nullptr, wave * 16, 0, lane, acc);
    store_bf16(acc, vB, n0, wave, lane, N);
}

// ===========================================================================
// Edge conv: 64 edges/block, 512 threads, 8 waves col-split (16 cols/wave)
// (unchanged from R9/R10 — counters balanced)
// ===========================================================================
template<int FIN>
__global__ __launch_bounds__(512, 8)
void edge_conv8(const short* __restrict__ xB,
                const int* __restrict__ sSrc, const int* __restrict__ sDst,
                const short* __restrict__ eaB, const float* __restrict__ sq,
                const short* __restrict__ uB, const short* __restrict__ vB,
                const short* __restrict__ W1pk, const short* __restrict__ W2pk,
                const float* __restrict__ b2,
                float* __restrict__ agg, int E, int swzQ, int swzR)
{
    constexpr int KPP  = FIN + 32;
    constexpr int FSTR = KPP + 8;        // 72 / 168
    constexpr int H1STR = 136;
    constexpr bool MBF = (FSTR >= 132);
    constexpr int MS = MBF ? FSTR : H1STR;
    __shared__ __align__(16) short feat[64 * FSTR];
    __shared__ __align__(16) short h1s[64 * H1STR];
    __shared__ int dstv[64];
    const int tid = threadIdx.x, lane = tid & 63, wave = tid >> 6;
    const int l15 = lane & 15, lg = lane >> 4;
    int bid = blockIdx.x;
    {
        const int xcd = bid & 7, idx = bid >> 3;
        bid = (xcd < swzR ? xcd * (swzQ + 1)
                          : swzR * (swzQ + 1) + (xcd - swzR) * swzQ) + idx;
    }
    const int e0 = bid * 64;
    const int c0 = wave * 16;

    {
        const int r = tid >> 3, s = tid & 7, e = e0 + r;
        short* frow = feat + r * FSTR;
        short* urow = h1s + r * H1STR;
        if (e < E) {
            const int si = sSrc[e], di = sDst[e];
            if (s == 0) dstv[r] = di;
            float sp = 0.f;
#pragma unroll
            for (int c = s; c < FIN / 8; c += 8) {
                const bf16x8 a = *(const bf16x8*)(xB + (size_t)si * FIN + c * 8);
                const bf16x8 b = *(const bf16x8*)(xB + (size_t)di * FIN + c * 8);
                float p[8];
#pragma unroll
                for (int jj = 0; jj < 8; ++jj) {
                    p[jj] = bf2f(a[jj]) * bf2f(b[jj]);
                    sp += p[jj];
                }
                uint4 w;
                w.x = cvt_pk(p[0], p[1]); w.y = cvt_pk(p[2], p[3]);
                w.z = cvt_pk(p[4], p[5]); w.w = cvt_pk(p[6], p[7]);
                *(uint4*)(frow + c * 8) = w;
            }
            sp += __shfl_xor(sp, 1); sp += __shfl_xor(sp, 2); sp += __shfl_xor(sp, 4);
            if (s == 0) {
                const float e1v = sqrtf(fmaxf(sq[si] + sq[di] - 2.f * sp, 0.f));
                *(unsigned*)(frow + FIN) = cvt_pk(e1v, sp);
            }
            if (s == 1) {
                const short4 ea = *(const short4*)(eaB + (size_t)e * 4);
                *(short2*)(frow + FIN + 2) = make_short2(ea.x, ea.y);
                *(short2*)(frow + FIN + 4) = make_short2(ea.z, ea.w);
            }
            for (int d = FIN + 6 + s; d < KPP; d += 8) frow[d] = 0;
#pragma unroll
            for (int c = s; c < 16; c += 8) {
                const bf16x8 uu = *(const bf16x8*)(uB + (size_t)di * 128 + c * 8);
                const bf16x8 vv = *(const bf16x8*)(vB + (size_t)si * 128 + c * 8);
                float o[8];
#pragma unroll
                for (int jj = 0; jj < 8; ++jj)
                    o[jj] = bf2f(uu[jj]) + bf2f(vv[jj]);
                uint4 w;
                w.x = cvt_pk(o[0], o[1]); w.y = cvt_pk(o[2], o[3]);
                w.z = cvt_pk(o[4], o[5]); w.w = cvt_pk(o[6], o[7]);
                *(uint4*)(urow + c * 8) = w;
            }
        } else {
            if (s == 0) dstv[r] = -1;
            for (int d = s * 4; d < KPP; d += 32) *(short4*)(frow + d) = make_short4(0, 0, 0, 0);
            for (int d = s * 4; d < 128; d += 32) *(short4*)(urow + d) = make_short4(0, 0, 0, 0);
        }
    }
    __syncthreads();

    f32x4 acc[4];
#pragma unroll
    for (int sb = 0; sb < 4; ++sb) acc[sb] = (f32x4){0.f, 0.f, 0.f, 0.f};
    {
        const short* wb = W1pk + (size_t)(c0 + l15) * 32 + lg * 8;
#pragma unroll
        for (int ks = 0; ks < KPP / 32; ++ks) {
            const bf16x8 bv = *(const bf16x8*)(wb + (size_t)ks * 4096);
#pragma unroll
            for (int sb = 0; sb < 4; ++sb) {
                const bf16x8 av =
                    *(const bf16x8*)(feat + (sb * 16 + l15) * FSTR + ks * 32 + lg * 8);
                acc[sb] = __builtin_amdgcn_mfma_f32_16x16x32_bf16(av, bv, acc[sb], 0, 0, 0);
            }
        }
    }
#pragma unroll
    for (int sb = 0; sb < 4; ++sb)
#pragma unroll
        for (int i = 0; i < 4; ++i) {
            const int row = sb * 16 + lg * 4 + i;
            const int col = c0 + l15;
            float vv = acc[sb][i] + bf2f(h1s[row * H1STR + col]);
            vv = fmaxf(vv, 0.0f);
            const float o = __shfl_xor(vv, 1);
            if (!(lane & 1))
                *(unsigned*)&h1s[row * H1STR + col] = cvt_pk(vv, o);
        }
    __syncthreads();

    {
        const float bv0 = b2[c0 + l15];
#pragma unroll
        for (int sb = 0; sb < 4; ++sb) acc[sb] = (f32x4){bv0, bv0, bv0, bv0};
    }
    {
        const short* wb = W2pk + (size_t)(c0 + l15) * 32 + lg * 8;
#pragma unroll
        for (int ks = 0; ks < 4; ++ks) {
            const bf16x8 bv = *(const bf16x8*)(wb + (size_t)ks * 4096);
#pragma unroll
            for (int sb = 0; sb < 4; ++sb) {
                const bf16x8 av =
                    *(const bf16x8*)(h1s + (sb * 16 + l15) * H1STR + ks * 32 + lg * 8);
                acc[sb] = __builtin_amdgcn_mfma_f32_16x16x32_bf16(av, bv, acc[sb], 0, 0, 0);
            }
        }
    }
    short* mb = MBF ? feat : h1s;
    if (!MBF) __syncthreads();
#pragma unroll
    for (int sb = 0; sb < 4; ++sb)
#pragma unroll
        for (int i = 0; i < 4; ++i) {
            const int row = sb * 16 + lg * 4 + i;
            const int col = c0 + l15;
            const float vv = fmaxf(acc[sb][i], 0.0f);
            const float o = __shfl_xor(vv, 1);
            if (!(lane & 1))
                *(unsigned*)&mb[row * MS + col] = cvt_pk(vv, o);
        }
    __syncthreads();

    {
        const int c  = tid & 127;
        const int rh = tid >> 7;
        int cur = -1;
        float mx = 0.0f;
#pragma unroll 4
        for (int i2 = 0; i2 < 16; ++i2) {
            const int row = rh * 16 + i2;
            const int d = dstv[row];
            const float val = bf2f(mb[row * MS + c]);
            if (d != cur) {
                if (cur >= 0 && mx > 0.f)
                    atomicMax((int*)agg + (size_t)cur * 128 + c, __float_as_int(mx));
                cur = d;
                mx = val;
            } else {
                mx = fmaxf(mx, val);
            }
        }
        if (cur >= 0 && mx > 0.f)
            atomicMax((int*)agg + (size_t)cur * 128 + c, __float_as_int(mx));
    }
}

// ===========================================================================
// Fused node MLP + next-layer uv precompute, COLUMN-SPLIT.
// 64 rows/block, 512 threads, 8 waves x 16 cols.
// y = relu(relu([x,agg]@W1+b1)@W2+b2) (+x); out=y; xB=bf16(y); sq=||y||^2;
// u = y@WdN+b1N; v = y@WbN.  Also zeroes agg rows for the next edge pass.
// ===========================================================================
template<int FIN, int KP, int FSTR, bool RES>
__global__ __launch_bounds__(512, 4)
void node_uv(const float* __restrict__ xin, const float* __restrict__ agg,
             const short* __restrict__ W1pk, const float* __restrict__ b1,
             const short* __restrict__ W2pk, const float* __restrict__ b2,
             float* __restrict__ out,
             const short* __restrict__ WdN, const float* __restrict__ b1N,
             const short* __restrict__ WbN,
             short* __restrict__ uB, short* __restrict__ vB,
             float* __restrict__ sq, short* __restrict__ xB,
             float* __restrict__ aggz, int N)
{
    constexpr int H1STR = 136;
    __shared__ __align__(16) short feat[64 * FSTR];
    __shared__ __align__(16) short h1s[64 * H1STR];
    __shared__ float sqp[8][64];
    const int tid = threadIdx.x, lane = tid & 63, wave = tid >> 6;
    const int l15 = lane & 15, lg = lane >> 4;
    const int n0 = blockIdx.x * 64;
    const int c0 = wave * 16;

    {   // stage feat = [bf16(x), bf16(agg)] (8 threads/row)
        const int r = tid >> 3, s = tid & 7, n = n0 + r;
        short* frow = feat + r * FSTR;
        if (n < N) {
            const float4* xr = (const float4*)(xin + (size_t)n * FIN);
            const float4* ar = (const float4*)(agg + (size_t)n * 128);
#pragma unroll
            for (int d4 = s; d4 < FIN / 4; d4 += 8)
                *(uint2*)(frow + d4 * 4) = pk4(xr[d4]);
#pragma unroll
            for (int d4 = s; d4 < 32; d4 += 8)
                *(uint2*)(frow + FIN + d4 * 4) = pk4(ar[d4]);
        } else {
            for (int d = s * 4; d < KP; d += 32) *(short4*)(frow + d) = make_short4(0, 0, 0, 0);
        }
    }
    __syncthreads();

    f32x4 acc[4];
    // ---- GEMM1 (K=KP, col-split) ----
    {
        const float bv = b1[c0 + l15];
#pragma unroll
        for (int sb = 0; sb < 4; ++sb) acc[sb] = (f32x4){bv, bv, bv, bv};
        const short* wb = W1pk + (size_t)(c0 + l15) * 32 + lg * 8;
#pragma unroll
        for (int ks = 0; ks < KP / 32; ++ks) {
            const bf16x8 bw = *(const bf16x8*)(wb + (size_t)ks * 4096);
#pragma unroll
            for (int sb = 0; sb < 4; ++sb) {
                const bf16x8 av =
                    *(const bf16x8*)(feat + (sb * 16 + l15) * FSTR + ks * 32 + lg * 8);
                acc[sb] = __builtin_amdgcn_mfma_f32_16x16x32_bf16(av, bw, acc[sb], 0, 0, 0);
            }
        }
    }
#pragma unroll
    for (int sb = 0; sb < 4; ++sb)
#pragma unroll
        for (int i = 0; i < 4; ++i) {
            const int row = sb * 16 + lg * 4 + i;
            const float vv = fmaxf(acc[sb][i], 0.f);
            const float o = __shfl_xor(vv, 1);
            if (!(lane & 1))
                *(unsigned*)&h1s[row * H1STR + c0 + l15] = cvt_pk(vv, o);
        }
    __syncthreads();
    // ---- GEMM2 (K=128, col-split) ----
    {
        const float bv = b2[c0 + l15];
#pragma unroll
        for (int sb = 0; sb < 4; ++sb) acc[sb] = (f32x4){bv, bv, bv, bv};
        const short* wb = W2pk + (size_t)(c0 + l15) * 32 + lg * 8;
#pragma unroll
        for (int ks = 0; ks < 4; ++ks) {
            const bf16x8 bw = *(const bf16x8*)(wb + (size_t)ks * 4096);
#pragma unroll
            for (int sb = 0; sb < 4; ++sb) {
                const bf16x8 av =
                    *(const bf16x8*)(h1s + (sb * 16 + l15) * H1STR + ks * 32 + lg * 8);
                acc[sb] = __builtin_amdgcn_mfma_f32_16x16x32_bf16(av, bw, acc[sb], 0, 0, 0);
            }
        }
    }
    // ---- y = relu (+res); global stores ----
#pragma unroll
    for (int sb = 0; sb < 4; ++sb)
#pragma unroll
        for (int i = 0; i < 4; ++i) {
            const int row = sb * 16 + lg * 4 + i;
            const int n = n0 + row;
            const int c = c0 + l15;
            float v = fmaxf(acc[sb][i], 0.f);
            if (RES && n < N) v += xin[(size_t)n * 128 + c];
            acc[sb][i] = v;
            const float o = __shfl_xor(v, 1);
            if (!(lane & 1) && n < N) {
                *(float2*)&out[(size_t)n * 128 + c] = make_float2(v, o);
                *(unsigned*)&xB[(size_t)n * 128 + c] = cvt_pk(v, o);
            }
        }
    __syncthreads();                 // all GEMM2 h1s reads complete
    // ---- y -> h1s (bf16), sq partials ----
#pragma unroll
    for (int sb = 0; sb < 4; ++sb)
#pragma unroll
        for (int i = 0; i < 4; ++i) {
            const int row = sb * 16 + lg * 4 + i;
            const float v = acc[sb][i];
            const float o = __shfl_xor(v, 1);
            if (!(lane & 1))
                *(unsigned*)&h1s[row * H1STR + c0 + l15] = cvt_pk(v, o);
            float t = v * v;
            t += __shfl_xor(t, 1); t += __shfl_xor(t, 2);
            t += __shfl_xor(t, 4); t += __shfl_xor(t, 8);
            if (l15 == 0) sqp[wave][row] = t;
        }
    __syncthreads();
    // ---- sq write + agg zero ----
    if (tid < 64) {
        const int n = n0 + tid;
        if (n < N) {
            float s = 0.f;
#pragma unroll
            for (int w = 0; w < 8; ++w) s += sqp[w][tid];
            sq[n] = s;
        }
    }
    {
        float4 z = {0.f, 0.f, 0.f, 0.f};
        float4* ap = (float4*)(aggz + (size_t)n0 * 128);
#pragma unroll
        for (int i = 0; i < 4; ++i) ap[tid + i * 512] = z;
    }
    // ---- u GEMM (K=128) ----
    {
        const float bv = b1N[c0 + l15];
#pragma unroll
        for (int sb = 0; sb < 4; ++sb) acc[sb] = (f32x4){bv, bv, bv, bv};
        const short* wb = WdN + (size_t)(c0 + l15) * 32 + lg * 8;
#pragma unroll
        for (int ks = 0; ks < 4; ++ks) {
            const bf16x8 bw = *(const bf16x8*)(wb + (size_t)ks * 4096);
#pragma unroll
            for (int sb = 0; sb < 4; ++sb) {
                const bf16x8 av =
                    *(const bf16x8*)(h1s + (sb * 16 + l15) * H1STR + ks * 32 + lg * 8);
                acc[sb] = __builtin_amdgcn_mfma_f32_16x16x32_bf16(av, bw, acc[sb], 0, 0, 0);
            }
        }
#pragma unroll
        for (int sb = 0; sb < 4; ++sb)
#pragma unroll
            for (int i = 0; i < 4; ++i) {
                const int n = n0 + sb * 16 + lg * 4 + i;
                const float v = acc[sb][i];
                const float o = __shfl_xor(v, 1);
                if (!(lane & 1) && n < N)
                    *(unsigned*)&uB[(size_t)n * 128 + c0 + l15] = cvt_pk(v, o);
            }
    }
    // ---- v GEMM (K=128) ----
    {
#pragma unroll
        for (int sb = 0; sb < 4; ++sb) acc[sb] = (f32x4){0.f, 0.f, 0.f, 0.f};
        const short* wb = WbN + (size_t)(c0 + l15) * 32 + lg * 8;
#pragma unroll
        for (int ks = 0; ks < 4; ++ks) {
            const bf16x8 bw = *(const bf16x8*)(wb + (size_t)ks * 4096);
#pragma unroll
            for (int sb = 0; sb < 4; ++sb) {
                const bf16x8 av =
                    *(const bf16x8*)(h1s + (sb * 16 + l15) * H1STR + ks * 32 + lg * 8);
                acc[sb] = __builtin_amdgcn_mfma_f32_16x16x32_bf16(av, bw, acc[sb], 0, 0, 0);
            }
        }
#pragma unroll
        for (int sb = 0; sb < 4; ++sb)
#pragma unroll
            for (int i = 0; i < 4; ++i) {
                const int n = n0 + sb * 16 + lg * 4 + i;
                const float v = acc[sb][i];
                const float o = __shfl_xor(v, 1);
                if (!(lane & 1) && n < N)
                    *(unsigned*)&vB[(size_t)n * 128 + c0 + l15] = cvt_pk(v, o);
            }
    }
}

// ===========================================================================
// Fused layer-3 node MLP + fusion MLP, COLUMN-SPLIT.
// 32 rows/block, 512 threads, 8 waves.
// x3 = relu(relu([x2,agg]@W1+b1)@W2+b2)+x2 (registers);
// out = relu(relu([x1,x2,x3]@fW1+fb1)@fW2+fb2).
// ===========================================================================
__global__ __launch_bounds__(512, 4)
void node_fusion(const float* __restrict__ x1, const float* __restrict__ x2,
                 const float* __restrict__ agg,
                 const short* __restrict__ W1pk, const float* __restrict__ b1,
                 const short* __restrict__ W2pk, const float* __restrict__ b2,
                 const short* __restrict__ fW1, const float* __restrict__ fb1,
                 const short* __restrict__ fW2, const float* __restrict__ fb2,
                 float* __restrict__ out, int N)
{
    constexpr int NSTR = 264;     // node feat stride (K=256)
    constexpr int H1N  = 136;     // node h1 stride
    constexpr int FSF  = 392;     // fusion feat stride (K=384)
    constexpr int H1F  = 264;     // fusion h1 stride (256 cols)
    __shared__ __align__(16) short sh[32 * FSF + 32 * H1F];
    short* featN = sh;
    short* featF = sh;
    short* h1N   = sh + 32 * FSF;
    short* h1F   = sh + 32 * FSF;
    const int tid = threadIdx.x, lane = tid & 63, wave = tid >> 6;
    const int l15 = lane & 15, lg = lane >> 4;
    const int n0 = blockIdx.x * 32;
    const int c0 = wave * 16;

    {   // stage featN = [bf16(x2), bf16(agg)] (16 threads/row)
        const int r = tid >> 4, s = tid & 15, n = n0 + r;
        short* frow = featN + r * NSTR;
        if (n < N) {
            const float4* xr = (const float4*)(x2 + (size_t)n * 128);
            const float4* ar = (const float4*)(agg + (size_t)n * 128);
#pragma unroll
            for (int d4 = s; d4 < 32; d4 += 16) {
                *(uint2*)(frow + d4 * 4)       = pk4(xr[d4]);
                *(uint2*)(frow + 128 + d4 * 4) = pk4(ar[d4]);
            }
        } else {
            for (int d = s * 4; d < 256; d += 64) *(short4*)(frow + d) = make_short4(0, 0, 0, 0);
        }
    }
    __syncthreads();

    f32x4 acc[2];
    // ---- node GEMM1 (K=256, 128 cols col-split) ----
    {
        const float bv = b1[c0 + l15];
#pragma unroll
        for (int sb = 0; sb < 2; ++sb) acc[sb] = (f32x4){bv, bv, bv, bv};
        const short* wb = W1pk + (size_t)(c0 + l15) * 32 + lg * 8;
#pragma unroll
        for (int ks = 0; ks < 8; ++ks) {
            const bf16x8 bw = *(const bf16x8*)(wb + (size_t)ks * 4096);
#pragma unroll
            for (int sb = 0; sb < 2; ++sb) {
                const bf16x8 av =
                    *(const bf16x8*)(featN + (sb * 16 + l15) * NSTR + ks * 32 + lg * 8);
                acc[sb] = __builtin_amdgcn_mfma_f32_16x16x32_bf16(av, bw, acc[sb], 0, 0, 0);
            }
        }
    }
#pragma unroll
    for (int sb = 0; sb < 2; ++sb)
#pragma unroll
        for (int i = 0; i < 4; ++i) {
            const int row = sb * 16 + lg * 4 + i;
            const float vv = fmaxf(acc[sb][i], 0.f);
            const float o = __shfl_xor(vv, 1);
            if (!(lane & 1))
                *(unsigned*)&h1N[row * H1N + c0 + l15] = cvt_pk(vv, o);
        }
    __syncthreads();
    // ---- node GEMM2 (K=128) ----
    {
        const float bv = b2[c0 + l15];
#pragma unroll
        for (int sb = 0; sb < 2; ++sb) acc[sb] = (f32x4){bv, bv, bv, bv};
        const short* wb = W2pk + (size_t)(c0 + l15) * 32 + lg * 8;
#pragma unroll
        for (int ks = 0; ks < 4; ++ks) {
            const bf16x8 bw = *(const bf16x8*)(wb + (size_t)ks * 4096);
#pragma unroll
            for (int sb = 0; sb < 2; ++sb) {
                const bf16x8 av =
                    *(const bf16x8*)(h1N + (sb * 16 + l15) * H1N + ks * 32 + lg * 8);
                acc[sb] = __builtin_amdgcn_mfma_f32_16x16x32_bf16(av, bw, acc[sb], 0, 0, 0);
            }
        }
    }
    // y = x3 = relu + x2 (registers)
#pragma unroll
    for (int sb = 0; sb < 2; ++sb)
#pragma unroll
        for (int i = 0; i < 4; ++i) {
            const int n = n0 + sb * 16 + lg * 4 + i;
            float v = fmaxf(acc[sb][i], 0.f);
            if (n < N) v += x2[(size_t)n * 128 + c0 + l15];
            acc[sb][i] = v;
        }
    __syncthreads();          // featN + h1N reads done

    {   // stage featF = [bf16(x1), bf16(x2), *] (16 threads/row)
        const int r = tid >> 4, s = tid & 15, n = n0 + r;
        short* frow = featF + r * FSF;
        if (n < N) {
            const float4* a1 = (const float4*)(x1 + (size_t)n * 128);
            const float4* a2 = (const float4*)(x2 + (size_t)n * 128);
#pragma unroll
            for (int d4 = s; d4 < 32; d4 += 16) {
                *(uint2*)(frow + d4 * 4)       = pk4(a1[d4]);
                *(uint2*)(frow + 128 + d4 * 4) = pk4(a2[d4]);
            }
        } else {
            for (int d = s * 4; d < 384; d += 64) *(short4*)(frow + d) = make_short4(0, 0, 0, 0);
        }
    }
    // x3 from registers into featF cols [256,384)
#pragma unroll
    for (int sb = 0; sb < 2; ++sb)
#pragma unroll
        for (int i = 0; i < 4; ++i) {
            const int row = sb * 16 + lg * 4 + i;
            const float v = acc[sb][i];
            const float o = __shfl_xor(v, 1);
            if (!(lane & 1))
                *(unsigned*)&featF[row * FSF + 256 + c0 + l15] = cvt_pk(v, o);
        }
    __syncthreads();

    // ---- fusion GEMM1 (K=384, 256 cols: wave -> 32 cols) ----
    {
        const int cc0 = wave * 32;
        f32x4 a2[2][2];
#pragma unroll
        for (int f = 0; f < 2; ++f) {
            const float bv = fb1[cc0 + f * 16 + l15];
            a2[0][f] = (f32x4){bv, bv, bv, bv};
            a2[1][f] = (f32x4){bv, bv, bv, bv};
        }
        const short* wb = fW1 + (size_t)(cc0 + l15) * 32 + lg * 8;
#pragma unroll
        for (int ks = 0; ks < 12; ++ks) {
            const short* wp = wb + (size_t)ks * 8192;
            const bf16x8 bv0 = *(const bf16x8*)(wp);
            const bf16x8 bv1 = *(const bf16x8*)(wp + 512);
#pragma unroll
            for (int sb = 0; sb < 2; ++sb) {
                const bf16x8 av =
                    *(const bf16x8*)(featF + (sb * 16 + l15) * FSF + ks * 32 + lg * 8);
                a2[sb][0] = __builtin_amdgcn_mfma_f32_16x16x32_bf16(av, bv0, a2[sb][0], 0, 0, 0);
                a2[sb][1] = __builtin_amdgcn_mfma_f32_16x16x32_bf16(av, bv1, a2[sb][1], 0, 0, 0);
            }
        }
#pragma unroll
        for (int sb = 0; sb < 2; ++sb)
#pragma unroll
            for (int f = 0; f < 2; ++f)
#pragma unroll
                for (int i = 0; i < 4; ++i) {
                    const int row = sb * 16 + lg * 4 + i;
                    const int col = cc0 + f * 16 + l15;
                    const float vv = fmaxf(a2[sb][f][i], 0.f);
                    const float o = __shfl_xor(vv, 1);
                    if (!(lane & 1))
                        *(unsigned*)&h1F[row * H1F + col] = cvt_pk(vv, o);
                }
    }
    __syncthreads();
    // ---- fusion GEMM2 (K=256, 128 cols) ----
    {
        const float bv = fb2[c0 + l15];
#pragma unroll
        for (int sb = 0; sb < 2; ++sb) acc[sb] = (f32x4){bv, bv, bv, bv};
        const short* wb = fW2 + (size_t)(c0 + l15) * 32 + lg * 8;
#pragma unroll
        for (int ks = 0; ks < 8; ++ks) {
            const bf16x8 bw = *(const bf16x8*)(wb + (size_t)ks * 4096);
#pragma unroll
            for (int sb = 0; sb < 2; ++sb) {
                const bf16x8 av =
                    *(const bf16x8*)(h1F + (sb * 16 + l15) * H1F + ks * 32 + lg * 8);
                acc[sb] = __builtin_amdgcn_mfma_f32_16x16x32_bf16(av, bw, acc[sb], 0, 0, 0);
            }
        }
    }
#pragma unroll
    for (int sb = 0; sb < 2; ++sb)
#pragma unroll
        for (int i = 0; i < 4; ++i) {
            const int n = n0 + sb * 16 + lg * 4 + i;
            const float v = fmaxf(acc[sb][i], 0.f);
            const float o = __shfl_xor(v, 1);
            if (!(lane & 1) && n < N)
                *(float2*)&out[(size_t)n * 128 + c0 + l15] = make_float2(v, o);
        }
}

// ===========================================================================
extern "C" void kernel_launch(void* const* d_in, const int* in_sizes, int n_in,
                              void* d_out, int out_size, void* d_ws, size_t ws_size,
                              hipStream_t stream)
{
    const float* x    = (const float*)d_in[0];
    const int*   eidx = (const int*)d_in[1];
    const float* ea   = (const float*)d_in[2];

    const float* c1_eW1 = (const float*)d_in[3];
    const float* c1_eb1 = (const float*)d_in[4];
    const float* c1_eW2 = (const float*)d_in[5];
    const float* c1_eb2 = (const float*)d_in[6];
    const float* c1_lW1 = (const float*)d_in[7];
    const float* c1_lb1 = (const float*)d_in[8];
    const float* c1_lW2 = (const float*)d_in[9];
    const float* c1_lb2 = (const float*)d_in[10];

    const float* c2_eW1 = (const float*)d_in[11];
    const float* c2_eb1 = (const float*)d_in[12];
    const float* c2_eW2 = (const float*)d_in[13];
    const float* c2_eb2 = (const float*)d_in[14];
    const float* c2_lW1 = (const float*)d_in[15];
    const float* c2_lb1 = (const float*)d_in[16];
    const float* c2_lW2 = (const float*)d_in[17];
    const float* c2_lb2 = (const float*)d_in[18];

    const float* c3_eW1 = (const float*)d_in[19];
    const float* c3_eb1 = (const float*)d_in[20];
    const float* c3_eW2 = (const float*)d_in[21];
    const float* c3_eb2 = (const float*)d_in[22];
    const float* c3_lW1 = (const float*)d_in[23];
    const float* c3_lb1 = (const float*)d_in[24];
    const float* c3_lW2 = (const float*)d_in[25];
    const float* c3_lb2 = (const float*)d_in[26];

    const float* fus_W1 = (const float*)d_in[27];
    const float* fus_b1 = (const float*)d_in[28];
    const float* fus_W2 = (const float*)d_in[29];
    const float* fus_b2 = (const float*)d_in[30];

    const int N = in_sizes[0] / 32;   // 25000
    const int E = in_sizes[1] / 2;    // 400000
    const int* srcI = eidx;
    const int* dstI = eidx + E;

    const size_t NP  = (size_t)N * 128;
    const size_t NPA = (size_t)25024 * 128;     // agg padded to block multiple
    float* ws  = (float*)d_ws;
    float* x1  = ws;
    float* x2  = x1 + NP;
    float* agg = x2 + NP;
    float* sq  = agg + NPA;
    int* cursor = (int*)(sq + 25024);
    int* sSrc   = cursor + 25024;
    int* sDst   = sSrc + E;
    short* eaB  = (short*)(sDst + E);
    short* uB   = eaB + (size_t)E * 4;
    short* vB   = uB + NP;
    short* xB   = vB + NP;
    short* wpk  = xB + NP;

    // packed-weight offsets (shorts)
    short* e1Wd = wpk + 0;        // KIN 32  KP 32   (W1a-W1b)
    short* e1Wb = wpk + 4096;     // KIN 32  KP 32   (W1b)
    short* e1Wp = wpk + 8192;     // KIN 38  KP 64   (p rows + e1,e2,ea)
    short* e1W2 = wpk + 16384;    // KIN 128 KP 128
    short* e2Wd = wpk + 32768;    // KIN 128 KP 128
    short* e2Wb = wpk + 49152;
    short* e2Wp = wpk + 65536;    // KIN 134 KP 160
    short* e2W2 = wpk + 86016;
    short* e3Wd = wpk + 102400;
    short* e3Wb = wpk + 118784;
    short* e3Wp = wpk + 135168;
    short* e3W2 = wpk + 155648;
    short* n1W1 = wpk + 172032;   // KIN 160 KP 160
    short* n1W2 = wpk + 192512;
    short* n2W1 = wpk + 208896;   // KIN 256 KP 256
    short* n2W2 = wpk + 241664;
    short* n3W1 = wpk + 258048;
    short* n3W2 = wpk + 290816;
    short* fW1  = wpk + 307200;   // KIN 384 NOUT 256
    short* fW2  = wpk + 405504;   // KIN 256
    const int packTotal = 438272;

    PackJobs pj;
    const float* pw[NPACK] = {
        c1_eW1, c1_eW1 + 32 * 128, c1_eW1 + 64 * 128, c1_eW2,
        c2_eW1, c2_eW1 + 128 * 128, c2_eW1 + 256 * 128, c2_eW2,
        c3_eW1, c3_eW1 + 128 * 128, c3_eW1 + 256 * 128, c3_eW2,
        c1_lW1, c1_lW2, c2_lW1, c2_lW2, c3_lW1, c3_lW2,
        fus_W1, fus_W2};
    const float* ps[NPACK] = {
        c1_eW1 + 32 * 128, nullptr, nullptr, nullptr,
        c2_eW1 + 128 * 128, nullptr, nullptr, nullptr,
        c3_eW1 + 128 * 128, nullptr, nullptr, nullptr,
        nullptr, nullptr, nullptr, nullptr, nullptr, nullptr,
        nullptr, nullptr};
    const int pk_kin[NPACK]  = {32, 32, 38, 128, 128, 128, 134, 128,
                                128, 128, 134, 128, 160, 128, 256, 128, 256, 128,
                                384, 256};
    const int pk_nout[NPACK] = {128, 128, 128, 128, 128, 128, 128, 128,
                                128, 128, 128, 128, 128, 128, 128, 128, 128, 128,
                                256, 128};
    const int pk_end[NPACK]  = {4096, 8192, 16384, 32768, 49152, 65536, 86016, 102400,
                                118784, 135168, 155648, 172032, 192512, 208896, 241664,
                                258048, 290816, 307200, 405504, 438272};
    for (int i = 0; i < NPACK; ++i) {
        pj.W[i] = pw[i]; pj.Wsub[i] = ps[i];
        pj.KIN[i] = pk_kin[i]; pj.NOUT[i] = pk_nout[i]; pj.end[i] = pk_end[i];
    }
    pack_all<<<(packTotal + 255) / 256, 256, 0, stream>>>(pj, wpk, packTotal, cursor);

    // ---- sort edges by dst ----
    const int eblk = (E + 255) / 256;
    hist_kernel<<<eblk, 256, 0, stream>>>(dstI, cursor, E);
    scan_kernel<<<1, 1024, 0, stream>>>(cursor, N);
    scatter_kernel<<<eblk, 256, 0, stream>>>(srcI, dstI, ea, cursor, sSrc, sDst, eaB, E);

    const int eblocks = (E + 63) / 64;
    const int nblocks = (N + 63) / 64;
    const int fblocks = (N + 31) / 32;
    const int swzQ = eblocks / 8, swzR = eblocks % 8;

    // ---- layer 1 (FIN=32) ----
    uv_pre<32, 40><<<nblocks, 256, 0, stream>>>(
        x, e1Wd, c1_eb1, e1Wb, uB, vB, sq, xB, agg, N);
    edge_conv8<32><<<eblocks, 512, 0, stream>>>(
        xB, sSrc, sDst, eaB, sq, uB, vB, e1Wp, e1W2, c1_eb2, agg, E, swzQ, swzR);
    node_uv<32, 160, 168, false><<<nblocks, 512, 0, stream>>>(
        x, agg, n1W1, c1_lb1, n1W2, c1_lb2, x1,
        e2Wd, c2_eb1, e2Wb, uB, vB, sq, xB, agg, N);

    // ---- layer 2 (FIN=128, residual) ----
    edge_conv8<128><<<eblocks, 512, 0, stream>>>(
        xB, sSrc, sDst, eaB, sq, uB, vB, e2Wp, e2W2, c2_eb2, agg, E, swzQ, swzR);
    node_uv<128, 256, 264, true><<<nblocks, 512, 0, stream>>>(
        x1, agg, n2W1, c2_lb1, n2W2, c2_lb2, x2,
        e3Wd, c3_eb1, e3Wb, uB, vB, sq, xB, agg, N);

    // ---- layer 3 (FIN=128, residual) + fusion ----
    edge_conv8<128><<<eblocks, 512, 0, stream>>>(
        xB, sSrc, sDst, eaB, sq, uB, vB, e3Wp, e3W2, c3_eb2, agg, E, swzQ, swzR);
    node_fusion<<<fblocks, 512, 0, stream>>>(
        x1, x2, agg, n3W1, c3_lb1, n3W2, c3_lb2,
        fW1, fus_b1, fW2, fus_b2, (float*)d_out, N);
}